// Round 4
// baseline (378.002 us; speedup 1.0000x reference)
//
#include <hip/hip_runtime.h>
#include <stdint.h>
#include <stddef.h>
#include <math.h>

// SplitConv4Pim forward on MI355X — group-per-wave implicit-GEMM conv.
// Block 128m x 128oc, 8 waves = 2 oc-positions x 4 groups; per-wave 128x64 psum,
// in-register quantize, int8 LDS cross-group reduction.
// ws layout: [wq bf16: 4,718,592 B][xt bf16: 27,557,888 B]

typedef __bf16 bf16_t;
typedef __bf16 bf16x8 __attribute__((ext_vector_type(8)));
typedef float  f32x4  __attribute__((ext_vector_type(4)));

#define WS_XT_OFF 4718592

__device__ __forceinline__ void gload16(const void* g, void* l) {
  __builtin_amdgcn_global_load_lds(
      (const __attribute__((address_space(1))) uint32_t*)g,
      (__attribute__((address_space(3))) uint32_t*)l, 16, 0, 0);
}

// ---- P1: weight quantization: w[o][ic][ky][kx] f32 -> wq[o][kpos][ic] bf16 ----
__global__ void quant_w_k(const float* __restrict__ w,
                          const float* __restrict__ wsc,
                          bf16_t* __restrict__ wqo) {
  int idx = blockIdx.x * 256 + threadIdx.x;   // 1024*9*256 threads
  int ic   = idx & 255;
  int t2   = idx >> 8;
  int kpos = t2 % 9;
  int o    = t2 / 9;
  const float gw = (float)(1.0 / sqrt(294912.0 * 127.0));  // LSQ grad-scale
  float s0 = wsc[ic >> 5];
  float s  = s0 * gw + s0 * (1.0f - gw);      // forward-exact grad_scale fold
  float wv = w[o * 2304 + ic * 9 + kpos];
  float wi = rintf(wv / s);
  wi = fminf(127.f, fmaxf(-128.f, wi));
  int u = (int)wi + 128;
  int q = (u >> 6) & 3;
  float wsplit = (float)(q * 64 - 128);
  wqo[idx] = (bf16_t)(wsplit * s);
}

// ---- P2: x NCHW f32 -> padded NHWC bf16 xt[16][58][58][256] ----
__global__ void pad_x_k(const float* __restrict__ x, bf16_t* __restrict__ xt) {
  __shared__ bf16_t tile[56 * 258];
  int b  = blockIdx.x / 58;
  int yo = blockIdx.x % 58;
  int t  = threadIdx.x;
  bf16_t* dst = xt + (size_t)(b * 58 + yo) * 58 * 256;
  if (yo == 0 || yo == 57) {
    for (int i = 0; i < 58; ++i) dst[i * 256 + t] = (bf16_t)0.0f;
    return;
  }
  const float* src = x + (size_t)b * 256 * 3136 + (yo - 1) * 56;
  for (int i = 0; i < 56 * 256; i += 256) {
    int lin = i + t;
    int c  = lin / 56;
    int xx = lin - c * 56;
    tile[xx * 258 + c] = (bf16_t)src[c * 3136 + xx];
  }
  __syncthreads();
  for (int xo = 0; xo < 58; ++xo) {
    bf16_t v = (bf16_t)0.0f;
    if (xo >= 1 && xo <= 56) v = tile[(xo - 1) * 258 + t];
    dst[xo * 256 + t] = v;
  }
}

// ---- main conv ----
// grid 784 = 392 m-tiles x 2 oc-blocks; 512 threads.
// K-tiles: 72 = 9 taps x 8 ic32-blocks. LDS buffer 40 KB = A[4g][8frag][64lane][16B]
// (32 KB) + B[8frag][64lane][16B] (8 KB); triple-buffered = 120 KB; epilogue red
// [2pos][4g][128m][64oc] int8 = 64 KB overlaid.
__global__ __launch_bounds__(512, 2)
void conv_q_k(const bf16_t* __restrict__ xt, const bf16_t* __restrict__ wq,
              const float* __restrict__ ps, float* __restrict__ out) {
  __shared__ alignas(16) char lds[3 * 40960];

  const int tid  = threadIdx.x;
  const int lane = tid & 63;
  const int wv   = tid >> 6;
  const int g    = wv >> 1;                       // group 0..3
  const int pos  = wv & 1;                        // oc position (64-wide)

  // T1 XCD swizzle: 784 = 8 x 98; interleaved (m-tile, ocblk) so each XCD's
  // 49 m-tiles = exactly 2 batches -> x slice 3.4 MB fits its L2.
  const int bid    = blockIdx.x;
  const int s      = (bid & 7) * 98 + (bid >> 3);
  const int mt     = s >> 1;
  const int ocblk  = s & 1;
  const int m0     = mt << 7;
  const int ocbase = ocblk << 7;

  // ---- staging source addresses (fragment-major: LDS linear = fragment order) ----
  // A: 4 calls; global chunk for lds pos (c*512+tid):
  //   ga=idx>>9, frag=(idx>>6)&7, l=idx&63 -> row ga*256+ocbase+frag*16+(l&15),
  //   ic chunk ((l>>4)&3)*8. Per tile add kpos*256+icb*32.
  int wA[4];
#pragma unroll
  for (int c = 0; c < 4; ++c) {
    int idx = c * 512 + tid;
    int ga = idx >> 9, frag = (idx >> 6) & 7, l = idx & 63;
    int ocr = ocbase + frag * 16 + (l & 15);
    wA[c] = (ga * 256 + ocr) * 2304 + ((l >> 4) & 3) * 8;
  }
  // B: 1 call; mfrag=tid>>6, l=tid&63 -> m row mfrag*16+(l&15), ic chunk ((l>>4)&3)*8
  int xB;
  {
    int mr = ((tid >> 6) << 4) + (lane & 15);
    int gm = m0 + mr;
    int b = gm / 3136, rem = gm - b * 3136;
    int oy = rem / 56, ox = rem - oy * 56;
    xB = ((b * 58 + oy) * 58 + ox) * 256 + ((lane >> 4) & 3) * 8;
  }
  char* const myDst = &lds[0] + tid * 16;

  // ---- compute-side LDS read offsets (16 consecutive chunks per quarter-wave:
  //      conflict-free by construction) ----
  const int aRd = ((g * 8 + pos * 4) * 64 + lane) * 16;   // + io*1024
  const int bRd = 32768 + lane * 16;                       // + jm*1024

  f32x4 acc[4][8];                                         // [io oc][jm m]
#pragma unroll
  for (int i = 0; i < 4; ++i)
#pragma unroll
    for (int j = 0; j < 8; ++j)
#pragma unroll
      for (int k = 0; k < 4; ++k) acc[i][j][k] = 0.f;

  auto S_ALL = [&](int kt, int nb) {
    int kpos = kt >> 3, icb = kt & 7;
    int ky = kpos / 3, kx = kpos - ky * 3;
    int wof = kpos * 256 + icb * 32;
    int xof = ((ky * 58 + kx) << 8) + icb * 32;
    char* dst = myDst + nb * 40960;
#pragma unroll
    for (int c = 0; c < 4; ++c) gload16(wq + wA[c] + wof, dst + c * 8192);
    gload16(xt + xB + xof, dst + 32768);
  };

  auto body = [&](int t, int cur) {
    const char* buf = &lds[0] + cur * 40960;
    bf16x8 av[4], bv[8];
#pragma unroll
    for (int io = 0; io < 4; ++io) av[io] = *(const bf16x8*)(buf + aRd + io * 1024);
#pragma unroll
    for (int jm = 0; jm < 8; ++jm) bv[jm] = *(const bf16x8*)(buf + bRd + jm * 1024);
    if (t + 2 < 72) S_ALL(t + 2, (cur >= 1) ? cur - 1 : 2);
    __builtin_amdgcn_s_setprio(1);
#pragma unroll
    for (int io = 0; io < 4; ++io)
#pragma unroll
      for (int jm = 0; jm < 8; ++jm)
        acc[io][jm] = __builtin_amdgcn_mfma_f32_16x16x32_bf16(av[io], bv[jm], acc[io][jm], 0, 0, 0);
    __builtin_amdgcn_s_setprio(0);
    if (t < 70) asm volatile("s_waitcnt vmcnt(5)" ::: "memory");
    else        asm volatile("s_waitcnt vmcnt(0)" ::: "memory");
    __builtin_amdgcn_s_barrier();
  };

  // prologue: stage tiles 0,1; wait tile 0 complete (5 newer in flight)
  S_ALL(0, 0); S_ALL(1, 1);
  asm volatile("s_waitcnt vmcnt(5)" ::: "memory");
  __builtin_amdgcn_s_barrier();

#pragma unroll 1
  for (int tt = 0; tt < 24; ++tt) {
    body(3 * tt,     0);
    body(3 * tt + 1, 1);
    body(3 * tt + 2, 2);
  }

  // ---- epilogue: per-wave quantize own group's psum -> int8 -> LDS reduction ----
  const float gp = (float)(1.0 / sqrt(12845056.0 * 127.0));
  {
    float p0  = ps[g];
    float spu = p0 * gp + p0 * (1.0f - gp);
    float isp = 1.0f / spu;
    char* red = &lds[0];                         // [pos4g][128m][64oc] int8
    const int rr = lane & 15, hi = lane >> 4;
#pragma unroll
    for (int io = 0; io < 4; ++io)
#pragma unroll
      for (int jm = 0; jm < 8; ++jm) {
        uint32_t pk = 0;
#pragma unroll
        for (int k = 0; k < 4; ++k) {
          float q = rintf(acc[io][jm][k] * isp);
          q = fminf(127.f, fmaxf(-128.f, q));
          pk |= ((uint32_t)(((int)q) & 255)) << (8 * k);
        }
        int m   = jm * 16 + rr;
        int oc0 = io * 16 + (hi << 2);
        *(uint32_t*)(red + (pos * 4 + g) * 8192 + m * 64 + oc0) = pk;
      }
  }
  __syncthreads();
  {
    const char* red = &lds[0];
    const int m_l  = g * 32 + (lane >> 1);       // block-local m row
    const int och  = (lane & 1) << 5;            // oc offset 0/32
    float spus[4];
#pragma unroll
    for (int gg = 0; gg < 4; ++gg) {
      float p0 = ps[gg];
      spus[gg] = p0 * gp + p0 * (1.0f - gp);
    }
    float o[32];
#pragma unroll
    for (int j = 0; j < 32; ++j) o[j] = 0.f;
#pragma unroll
    for (int gg = 0; gg < 4; ++gg) {
      const char* rp = red + (pos * 4 + gg) * 8192 + m_l * 64 + och;
#pragma unroll
      for (int j = 0; j < 8; ++j) {
        uint32_t v = *(const uint32_t*)(rp + j * 4);
#pragma unroll
        for (int b2 = 0; b2 < 4; ++b2)
          o[j * 4 + b2] += (float)((int)(int8_t)(v >> (8 * b2))) * spus[gg];
      }
    }
    int gm = m0 + m_l;
    int b = gm / 3136, rem = gm - b * 3136;
    int oy = rem / 56, ox = rem - oy * 56;
    float* ob = out + b * 802816 + oy * 56 + ox;
    const int occ = ocbase + pos * 64 + och;
#pragma unroll
    for (int j = 0; j < 32; ++j) ob[(occ + j) * 3136] = o[j];
  }
}

extern "C" void kernel_launch(void* const* d_in, const int* in_sizes, int n_in,
                              void* d_out, int out_size, void* d_ws, size_t ws_size,
                              hipStream_t stream) {
  const float* x   = (const float*)d_in[0];   // [16,256,56,56]
  const float* w   = (const float*)d_in[1];   // [1024,256,3,3]
  const float* wsc = (const float*)d_in[2];   // [8]
  const float* ps  = (const float*)d_in[3];   // [4]
  float* out = (float*)d_out;                 // [16,256,56,56]
  bf16_t* wq = (bf16_t*)d_ws;
  bf16_t* xt = (bf16_t*)((char*)d_ws + WS_XT_OFF);

  quant_w_k<<<9216, 256, 0, stream>>>(w, wsc, wq);
  pad_x_k<<<16 * 58, 256, 0, stream>>>(x, xt);
  conv_q_k<<<784, 512, 0, stream>>>(xt, wq, ps, out);
}